// Round 16
// baseline (1452.976 us; speedup 1.0000x reference)
//
#include <hip/hip_runtime.h>
#include <hip/hip_bf16.h>
#include <math.h>

typedef __hip_bfloat16 bf16;
typedef __attribute__((ext_vector_type(8))) __bf16 bf16x8;
typedef __attribute__((ext_vector_type(4))) float f32x4;

#define NN 40962
#define NE 245760
#define HDIM 256
#define NH 8
#define CH 32

#define MT 64     // rows per block in MFMA kernels
#define KVB 512   // stage-1 blocks for sg_kv partial reduction

__device__ __forceinline__ float b2f(bf16 v) { return __bfloat162float(v); }
__device__ __forceinline__ bf16 f2b(float v) { return __float2bfloat16(v); }
__device__ __forceinline__ unsigned short f2bs(float v) {
  bf16 b = __float2bfloat16(v);
  return __builtin_bit_cast(unsigned short, b);
}
__device__ __forceinline__ float bs2f(unsigned short u) {
  return __bfloat162float(__builtin_bit_cast(bf16, u));
}

// gelu (tanh form) with native exp2: tanh(g) = (e^{2g}-1)/(e^{2g}+1)
__device__ __forceinline__ float fast_gelu(float x) {
  float x2 = x * x;
  float g = x * (0.7978845608028654f + 0.0356774081f * x2);
  float y = fminf(g * 2.885390081777927f, 60.f);   // 2*log2(e)*g, clamped
  float t = exp2f(y);
  float th = (t - 1.f) * __builtin_amdgcn_rcpf(t + 1.f);
  return 0.5f * x * (1.f + th);
}

// ---- MFMA edge input projection: e = attr @ epW + epb (K=16 zero-padded to 32) ------
__global__ __launch_bounds__(512) void k_edge_proj_mfma(
    const float* __restrict__ attr, const unsigned short* __restrict__ Weps,
    const float* __restrict__ bias, bf16* __restrict__ e) {
  __shared__ unsigned short At[MT][40];    // 64 x 32 (cols 16..31 zero) + pad
  __shared__ unsigned short O[MT][264];
  int tid = threadIdx.x, l = tid & 63, w = tid >> 6;
  int lr = l & 15, lk = l >> 4;
  int base = blockIdx.x * MT;              // NE % 64 == 0
  {
    int p = tid >> 3, q = tid & 7;         // 512 threads = 64 x 8 exactly
    if (q < 4) {
      float4 v = *reinterpret_cast<const float4*>(&attr[(size_t)(base + p) * 16 + q * 4]);
      unsigned short tmp[4] = {f2bs(v.x), f2bs(v.y), f2bs(v.z), f2bs(v.w)};
      *reinterpret_cast<uint2*>(&At[p][q * 4]) = *reinterpret_cast<const uint2*>(tmp);
    } else {
      unsigned short z[4] = {0, 0, 0, 0};
      *reinterpret_cast<uint2*>(&At[p][q * 4]) = *reinterpret_cast<const uint2*>(z);
    }
  }
  __syncthreads();

  int j0 = w * 32;
  f32x4 acc[4][2];
#pragma unroll
  for (int m = 0; m < 4; ++m)
#pragma unroll
    for (int n = 0; n < 2; ++n)
#pragma unroll
      for (int r = 0; r < 4; ++r) acc[m][n][r] = 0.f;
  {
    bf16x8 a[4], b[2];
#pragma unroll
    for (int m = 0; m < 4; ++m)
      a[m] = *reinterpret_cast<const bf16x8*>(&At[m * 16 + lr][lk * 8]);
#pragma unroll
    for (int n = 0; n < 2; ++n) {
      int nt = w * 2 + n;
      b[n] = *reinterpret_cast<const bf16x8*>(Weps + ((size_t)nt * 64 + l) * 8);
    }
#pragma unroll
    for (int m = 0; m < 4; ++m)
#pragma unroll
      for (int n = 0; n < 2; ++n)
        acc[m][n] = __builtin_amdgcn_mfma_f32_16x16x32_bf16(a[m], b[n], acc[m][n], 0, 0, 0);
  }
#pragma unroll
  for (int n = 0; n < 2; ++n) {
    int col = j0 + n * 16 + lr;
    float bv = bias[col];
#pragma unroll
    for (int m = 0; m < 4; ++m)
#pragma unroll
      for (int r = 0; r < 4; ++r)
        O[m * 16 + lk * 4 + r][col] = f2bs(acc[m][n][r] + bv);
  }
  __syncthreads();
  for (int t = tid; t < MT * 32; t += 512) {
    int p = t >> 5, c = t & 31;
    *reinterpret_cast<uint4*>(&e[(size_t)(base + p) * HDIM + c * 8]) =
        *reinterpret_cast<const uint4*>(&O[p][c * 8]);
  }
}

// ---- CSR build: count, scan(+cursor), fill (records pos[e] = CSR slot) --------------
__global__ void k_csr_count(const int* __restrict__ dst, int* __restrict__ cnt) {
  int e = blockIdx.x * 256 + threadIdx.x;
  if (e < NE) atomicAdd(&cnt[dst[e]], 1);
}
__global__ void k_csr_scan(const int* __restrict__ cnt, int* __restrict__ rowptr,
                           int* __restrict__ cursor) {
  __shared__ int part[256];
  __shared__ int tot;
  int t = threadIdx.x;
  const int CHUNK = (NN + 255) / 256;
  int lo = t * CHUNK, hi = lo + CHUNK; if (hi > NN) hi = NN; if (lo > NN) lo = NN;
  int s = 0;
  for (int i = lo; i < hi; ++i) s += cnt[i];
  part[t] = s;
  __syncthreads();
  if (t == 0) {
    int run = 0;
    for (int i = 0; i < 256; ++i) { int v = part[i]; part[i] = run; run += v; }
    tot = run;
  }
  __syncthreads();
  int run = part[t];
  for (int i = lo; i < hi; ++i) { rowptr[i] = run; cursor[i] = run; run += cnt[i]; }
  if (t == 0) rowptr[NN] = tot;
}
__global__ void k_csr_fill(const int* __restrict__ src, const int* __restrict__ dst,
                           int* __restrict__ cursor, int* __restrict__ csrsrc,
                           int* __restrict__ pos) {
  int e = blockIdx.x * 256 + threadIdx.x;
  if (e >= NE) return;
  int p = atomicAdd(&cursor[dst[e]], 1);
  csrsrc[p] = src[e];
  pos[e] = p;
}

// ---- fused weight swizzle (all matrices) + cnt zeroing ------------------------------
struct SwzP {
  const float *We0, *WeL, *Wl0, *Wr0, *Wq, *Wk, *Wv;
  const float *Wu1_0, *Wu1L, *Wu2_0, *Wu2L, *WlL, *WrL, *epW;
  unsigned short *wall, *w1s, *w2s, *w32s, *wep;
  int* cnt;
};
__device__ __forceinline__ void swz1(const float* __restrict__ W,
                                     unsigned short* __restrict__ out, int t, int Kdiv32) {
  int i = t & 7, l = (t >> 3) & 63;
  int k0 = (t >> 9) % Kdiv32;
  int n0 = t / (512 * Kdiv32);
  int k = k0 * 32 + (l >> 4) * 8 + i;
  int n = n0 * 16 + (l & 15);
  out[t] = f2bs(W[k * 256 + n]);
}
#define SWZ_NW (9 * 65536)
#define SWZ_N1 (3 * 81920)
#define SWZ_N2 (3 * 65536)
#define SWZ_N3 (6 * 8192)
#define SWZ_N4 8192
__global__ void k_swz_fused(SwzP P) {
  int gid = blockIdx.x * 256 + threadIdx.x;
  if (gid < SWZ_NW) {
    int mat = gid >> 16, t = gid & 65535;
    const float* W;
    switch (mat) {
      case 0: W = P.We0; break;
      case 1: W = P.WeL; break;
      case 2: W = P.WeL + 65536; break;
      case 3: W = P.WeL + 131072; break;
      case 4: W = P.Wl0; break;
      case 5: W = P.Wr0; break;
      case 6: W = P.Wq; break;
      case 7: W = P.Wk; break;
      default: W = P.Wv; break;
    }
    swz1(W, P.wall + (size_t)mat * 65536, t, 8);
  } else if (gid < SWZ_NW + SWZ_N1) {
    int idx = gid - SWZ_NW;
    int mat = idx / 81920, t = idx % 81920;
    const float* W = (mat == 0) ? P.Wu1_0 : P.Wu1L + (size_t)(mat - 1) * 81920;
    swz1(W, P.w1s + (size_t)mat * 81920, t, 10);
  } else if (gid < SWZ_NW + SWZ_N1 + SWZ_N2) {
    int idx = gid - SWZ_NW - SWZ_N1;
    int mat = idx >> 16, t = idx & 65535;
    const float* W = (mat == 0) ? P.Wu2_0 : P.Wu2L + (size_t)(mat - 1) * 65536;
    swz1(W, P.w2s + (size_t)mat * 65536, t, 8);
  } else if (gid < SWZ_NW + SWZ_N1 + SWZ_N2 + SWZ_N3) {
    int idx = gid - SWZ_NW - SWZ_N1 - SWZ_N2;
    int mat = idx >> 13, t = idx & 8191;
    int i = mat >> 1;
    const float* W = (mat & 1) ? P.WrL + (size_t)i * 8192 : P.WlL + (size_t)i * 8192;
    swz1(W, P.w32s + (size_t)mat * 8192, t, 1);
  } else if (gid < SWZ_NW + SWZ_N1 + SWZ_N2 + SWZ_N3 + SWZ_N4) {
    // epW [16][256] zero-padded to K=32 fragment layout
    int t = gid - (SWZ_NW + SWZ_N1 + SWZ_N2 + SWZ_N3);
    int i = t & 7, l = (t >> 3) & 63;
    int n0 = t >> 9;
    int k = (l >> 4) * 8 + i;
    int n = n0 * 16 + (l & 15);
    P.wep[t] = (k < 16) ? f2bs(P.epW[k * 256 + n]) : (unsigned short)0;
  } else {
    int i = gid - (SWZ_NW + SWZ_N1 + SWZ_N2 + SWZ_N3 + SWZ_N4);
    if (i < NN) P.cnt[i] = 0;
  }
}

// ---- MFMA edge score -> writes sxc[pos[e]*8+h] = exp(s)  (CSR-ordered) --------------
__global__ __launch_bounds__(512) void k_edge_score_mfma(
    const bf16* __restrict__ e, const unsigned short* __restrict__ Wes,
    const bf16* __restrict__ xl, const bf16* __restrict__ xr,
    const float* __restrict__ att, const int* __restrict__ src,
    const int* __restrict__ dst, const int* __restrict__ pos,
    float* __restrict__ sxc) {
  __shared__ unsigned short Ae[MT][264];   // e-tile, then reused as scoreboard
  __shared__ float attS[HDIM];
  __shared__ int sidx[MT], didx[MT];
  int tid = threadIdx.x, l = tid & 63, w = tid >> 6;
  int lr = l & 15, lk = l >> 4;
  int base = blockIdx.x * MT;
  if (tid < HDIM) attS[tid] = att[tid];
  if (tid < MT) sidx[tid] = src[base + tid];
  else if (tid < 2 * MT) didx[tid - MT] = dst[base + tid - MT];
  for (int t = tid; t < MT * 32; t += 512) {
    int p = t >> 5, c = t & 31;
    *reinterpret_cast<uint4*>(&Ae[p][c * 8]) =
        *reinterpret_cast<const uint4*>(&e[(size_t)(base + p) * HDIM + c * 8]);
  }
  __syncthreads();

  f32x4 acc[4][2];
#pragma unroll
  for (int m = 0; m < 4; ++m)
#pragma unroll
    for (int n = 0; n < 2; ++n)
#pragma unroll
      for (int r = 0; r < 4; ++r) acc[m][n][r] = 0.f;
  for (int k0 = 0; k0 < 8; ++k0) {
    bf16x8 a[4], b[2];
#pragma unroll
    for (int m = 0; m < 4; ++m)
      a[m] = *reinterpret_cast<const bf16x8*>(&Ae[m * 16 + lr][k0 * 32 + lk * 8]);
#pragma unroll
    for (int n = 0; n < 2; ++n) {
      int nt = w * 2 + n;
      b[n] = *reinterpret_cast<const bf16x8*>(Wes + ((size_t)(nt * 8 + k0) * 64 + l) * 8);
    }
#pragma unroll
    for (int m = 0; m < 4; ++m)
#pragma unroll
      for (int n = 0; n < 2; ++n)
        acc[m][n] = __builtin_amdgcn_mfma_f32_16x16x32_bf16(a[m], b[n], acc[m][n], 0, 0, 0);
  }
  __syncthreads();   // all Ae reads complete before scoreboard overwrite

  // epilogue: xl/xr read directly from global (L2-hot), scoreboard into Ae alias
#pragma unroll
  for (int n = 0; n < 2; ++n) {
    int col = w * 32 + n * 16 + lr;
    float av = attS[col];
#pragma unroll
    for (int m = 0; m < 4; ++m)
#pragma unroll
      for (int r = 0; r < 4; ++r) {
        int row = m * 16 + lk * 4 + r;
        float xs = b2f(xl[(size_t)sidx[row] * HDIM + col]) +
                   b2f(xr[(size_t)didx[row] * HDIM + col]);
        float mm = acc[m][n][r] + xs;
        mm = (mm > 0.f) ? mm : 0.2f * mm;
        Ae[row][col] = f2bs(mm * av);
      }
  }
  __syncthreads();
  for (int pair = tid; pair < MT * NH; pair += 512) {
    int ed = pair >> 3, h = pair & 7;
    float s = 0.f;
#pragma unroll
    for (int c = 0; c < CH; ++c) s += bs2f(Ae[ed][h * CH + c]);
    sxc[(size_t)pos[base + ed] * NH + h] = expf(s);
  }
}

// ---- fused CSR aggregate + node output + optional LN --------------------------------
// sxc is CSR-ordered: node n's ex values are contiguous at [rowptr[n]*8, rowptr[n+1]*8)
#define GCHUNK 64
template <int ID, bool LN>
__global__ __launch_bounds__(256) void k_gat_out(
    const int* __restrict__ rowptr, const int* __restrict__ csrsrc,
    const float* __restrict__ sxc, const bf16* __restrict__ xl,
    const float* __restrict__ x, const float* __restrict__ Wres,
    const float* __restrict__ bn, const float* __restrict__ lng,
    const float* __restrict__ lnb, float* __restrict__ xpre,
    float* __restrict__ xpost) {
  int n = blockIdx.x;
  int j = threadIdx.x;
  int h = j >> 5, c = j & 31;
  int p0 = rowptr[n], p1 = rowptr[n + 1];
  __shared__ int srcS[GCHUNK];
  __shared__ float exS[GCHUNK * NH];
  float a = 0.f, dsum = 0.f;
  for (int pb = p0; pb < p1; pb += GCHUNK) {
    int chunk = p1 - pb; if (chunk > GCHUNK) chunk = GCHUNK;
    if (j < chunk) srcS[j] = csrsrc[pb + j];
    for (int t = j; t < chunk * NH; t += 256) exS[t] = sxc[(size_t)pb * NH + t];
    __syncthreads();
    int i = 0;
    for (; i + 4 <= chunk; i += 4) {
      float e0 = exS[(i + 0) * NH + h], e1 = exS[(i + 1) * NH + h];
      float e2 = exS[(i + 2) * NH + h], e3 = exS[(i + 3) * NH + h];
      float x0 = b2f(xl[(size_t)srcS[i + 0] * HDIM + j]);
      float x1 = b2f(xl[(size_t)srcS[i + 1] * HDIM + j]);
      float x2 = b2f(xl[(size_t)srcS[i + 2] * HDIM + j]);
      float x3 = b2f(xl[(size_t)srcS[i + 3] * HDIM + j]);
      a += e0 * x0 + e1 * x1 + e2 * x2 + e3 * x3;
      dsum += e0 + e1 + e2 + e3;
    }
    for (; i < chunk; ++i) {
      float ev = exS[i * NH + h];
      a += ev * b2f(xl[(size_t)srcS[i] * HDIM + j]);
      dsum += ev;
    }
    __syncthreads();
  }
  __shared__ float oh[HDIM];
  __shared__ float rs[NH][CH];
  __shared__ float oc[CH + 1];
  oh[j] = a / (dsum + 1e-16f);
  const int KS = ID / NH;
  float r = 0.f;
  for (int k = h * KS; k < (h + 1) * KS; ++k)
    r += x[(size_t)n * ID + k] * Wres[k * CH + c];
  rs[h][c] = r;
  __syncthreads();
  if (j < CH) {
    float o = 0.f;
#pragma unroll
    for (int hh = 0; hh < NH; ++hh) o += oh[hh * CH + j];
    o *= (1.f / NH);
    float rr = 0.f;
#pragma unroll
    for (int hh = 0; hh < NH; ++hh) rr += rs[hh][j];
    o += rr + bn[j];
    xpre[(size_t)n * CH + j] = o;
    oc[j] = o;
  }
  __syncthreads();
  if (LN && j < CH) {
    float mu = 0.f;
#pragma unroll
    for (int k = 0; k < CH; ++k) mu += oc[k];
    mu *= (1.f / CH);
    float var = 0.f;
#pragma unroll
    for (int k = 0; k < CH; ++k) { float d = oc[k] - mu; var += d * d; }
    var *= (1.f / CH);
    xpost[(size_t)n * CH + j] = (oc[j] - mu) * rsqrtf(var + 1e-5f) * lng[j] + lnb[j];
  }
}

// ---- MFMA residual edge MLP (8 waves, aliased LDS; e_old kept in registers) ---------
__global__ __launch_bounds__(512) void k_edge_mlp_mfma(
    bf16* __restrict__ e, const float* __restrict__ xo,
    const int* __restrict__ src, const int* __restrict__ dst,
    const unsigned short* __restrict__ W1s, const float* __restrict__ bu1,
    const unsigned short* __restrict__ W2s, const float* __restrict__ bu2) {
  __shared__ unsigned short buf[MT][328];   // A1 (xo|e), then gelu(h1), then delta
  __shared__ int sidx[MT], didx[MT];
  int tid = threadIdx.x;
  int l = tid & 63;
  int w = tid >> 6;
  int base = blockIdx.x * MT;
  int lr = l & 15;
  int lk = l >> 4;

  if (tid < MT) sidx[tid] = src[base + tid];
  else if (tid < 2 * MT) didx[tid - MT] = dst[base + tid - MT];
  __syncthreads();

  for (int t = tid; t < MT * 32; t += 512) {
    int p = t >> 5, cc = t & 31;
    uint4 v = *reinterpret_cast<const uint4*>(&e[(size_t)(base + p) * HDIM + cc * 8]);
    *reinterpret_cast<uint4*>(&buf[p][64 + cc * 8]) = v;
  }
  for (int t = tid; t < MT * 64; t += 512) {
    int p = t >> 6, c = t & 63;
    float v = (c < CH) ? xo[(size_t)sidx[p] * CH + c]
                       : xo[(size_t)didx[p] * CH + (c - CH)];
    buf[p][c] = f2bs(v);
  }
  __syncthreads();

  // snapshot this thread's e_old store-slice into registers (bit-identical bytes;
  // avoids the global re-read after the gelu scatter overwrites LDS cols 64..255)
  uint4 eold[4];
#pragma unroll
  for (int it = 0; it < 4; ++it) {
    int t = tid + it * 512;
    int p = t >> 5, cc = t & 31;
    eold[it] = *reinterpret_cast<const uint4*>(&buf[p][64 + cc * 8]);
  }

  int j0 = w * 32;

  f32x4 acc[4][2];
#pragma unroll
  for (int m = 0; m < 4; ++m)
#pragma unroll
    for (int n = 0; n < 2; ++n)
#pragma unroll
      for (int r = 0; r < 4; ++r) acc[m][n][r] = 0.f;

  for (int k0 = 0; k0 < 10; ++k0) {
    bf16x8 a[4], b[2];
#pragma unroll
    for (int m = 0; m < 4; ++m)
      a[m] = *reinterpret_cast<const bf16x8*>(&buf[m * 16 + lr][k0 * 32 + lk * 8]);
#pragma unroll
    for (int n = 0; n < 2; ++n) {
      int nt = w * 2 + n;
      b[n] = *reinterpret_cast<const bf16x8*>(W1s + ((size_t)(nt * 10 + k0) * 64 + l) * 8);
    }
#pragma unroll
    for (int m = 0; m < 4; ++m)
#pragma unroll
      for (int n = 0; n < 2; ++n)
        acc[m][n] = __builtin_amdgcn_mfma_f32_16x16x32_bf16(a[m], b[n], acc[m][n], 0, 0, 0);
  }
  __syncthreads();   // all A1 reads complete before overwrite

  // gelu(h1 + bu1) -> buf alias (cols 0..255)
#pragma unroll
  for (int n = 0; n < 2; ++n) {
    float bv = bu1[j0 + n * 16 + lr];
#pragma unroll
    for (int m = 0; m < 4; ++m)
#pragma unroll
      for (int r = 0; r < 4; ++r) {
        float g = fast_gelu(acc[m][n][r] + bv);
        buf[m * 16 + lk * 4 + r][j0 + n * 16 + lr] = f2bs(g);
      }
  }
  __syncthreads();

#pragma unroll
  for (int m = 0; m < 4; ++m)
#pragma unroll
    for (int n = 0; n < 2; ++n)
#pragma unroll
      for (int r = 0; r < 4; ++r) acc[m][n][r] = 0.f;

  for (int k0 = 0; k0 < 8; ++k0) {
    bf16x8 a[4], b[2];
#pragma unroll
    for (int m = 0; m < 4; ++m)
      a[m] = *reinterpret_cast<const bf16x8*>(&buf[m * 16 + lr][k0 * 32 + lk * 8]);
#pragma unroll
    for (int n = 0; n < 2; ++n) {
      int nt = w * 2 + n;
      b[n] = *reinterpret_cast<const bf16x8*>(W2s + ((size_t)(nt * 8 + k0) * 64 + l) * 8);
    }
#pragma unroll
    for (int m = 0; m < 4; ++m)
#pragma unroll
      for (int n = 0; n < 2; ++n)
        acc[m][n] = __builtin_amdgcn_mfma_f32_16x16x32_bf16(a[m], b[n], acc[m][n], 0, 0, 0);
  }
  __syncthreads();   // all gelu reads done before delta overwrite

  // delta = acc + bu2 -> buf alias
#pragma unroll
  for (int n = 0; n < 2; ++n) {
    int col = j0 + n * 16 + lr;
    float bv = bu2[col];
#pragma unroll
    for (int m = 0; m < 4; ++m)
#pragma unroll
      for (int r = 0; r < 4; ++r)
        buf[m * 16 + lk * 4 + r][col] = f2bs(acc[m][n][r] + bv);
  }
  __syncthreads();

  // store: e_new = e_old (registers) + delta (LDS)
#pragma unroll
  for (int it = 0; it < 4; ++it) {
    int t = tid + it * 512;
    int p = t >> 5, cc = t & 31;
    uint4 dv = *reinterpret_cast<const uint4*>(&buf[p][cc * 8]);
    const unsigned short* dd = (const unsigned short*)&dv;
    const unsigned short* ee = (const unsigned short*)&eold[it];
    unsigned short ov[8];
#pragma unroll
    for (int i = 0; i < 8; ++i) ov[i] = f2bs(bs2f(ee[i]) + bs2f(dd[i]));
    *reinterpret_cast<uint4*>(&e[(size_t)(base + p) * HDIM + cc * 8]) =
        *reinterpret_cast<const uint4*>(ov);
  }
}

// ---- MFMA layer-0 node projection ---------------------------------------------------
__global__ __launch_bounds__(256) void k_node_proj0_mfma(
    const float* __restrict__ x, const unsigned short* __restrict__ Wls,
    const unsigned short* __restrict__ Wrs, bf16* __restrict__ xl,
    bf16* __restrict__ xr) {
  __shared__ unsigned short A[MT][264];
  __shared__ unsigned short O[MT][264];
  int tid = threadIdx.x, l = tid & 63, w = tid >> 6;
  int lr = l & 15, lk = l >> 4;
  int base = blockIdx.x * MT;
  for (int t = tid; t < MT * 64; t += 256) {
    int p = t >> 6, c = t & 63;
    int row = base + p; if (row >= NN) row = NN - 1;
    float4 v = *reinterpret_cast<const float4*>(&x[(size_t)row * HDIM + c * 4]);
    unsigned short tmp[4] = {f2bs(v.x), f2bs(v.y), f2bs(v.z), f2bs(v.w)};
    *reinterpret_cast<uint2*>(&A[p][c * 4]) = *reinterpret_cast<const uint2*>(tmp);
  }
  __syncthreads();
  int j0 = w * 64;
#pragma unroll
  for (int mtx = 0; mtx < 2; ++mtx) {
    const unsigned short* Ws = (mtx == 0) ? Wls : Wrs;
    bf16* outp = (mtx == 0) ? xl : xr;
    f32x4 acc[4][4];
#pragma unroll
    for (int m = 0; m < 4; ++m)
#pragma unroll
      for (int n = 0; n < 4; ++n)
#pragma unroll
        for (int r = 0; r < 4; ++r) acc[m][n][r] = 0.f;
    for (int k0 = 0; k0 < 8; ++k0) {
      bf16x8 a[4], b[4];
#pragma unroll
      for (int m = 0; m < 4; ++m)
        a[m] = *reinterpret_cast<const bf16x8*>(&A[m * 16 + lr][k0 * 32 + lk * 8]);
#pragma unroll
      for (int n = 0; n < 4; ++n) {
        int nt = (j0 >> 4) + n;
        b[n] = *reinterpret_cast<const bf16x8*>(Ws + ((size_t)(nt * 8 + k0) * 64 + l) * 8);
      }
#pragma unroll
      for (int m = 0; m < 4; ++m)
#pragma unroll
        for (int n = 0; n < 4; ++n)
          acc[m][n] = __builtin_amdgcn_mfma_f32_16x16x32_bf16(a[m], b[n], acc[m][n], 0, 0, 0);
    }
#pragma unroll
    for (int n = 0; n < 4; ++n)
#pragma unroll
      for (int m = 0; m < 4; ++m)
#pragma unroll
        for (int r = 0; r < 4; ++r)
          O[m * 16 + lk * 4 + r][j0 + n * 16 + lr] = f2bs(acc[m][n][r]);
    __syncthreads();
    for (int t = tid; t < MT * 32; t += 256) {
      int p = t >> 5, c = t & 31;
      if (base + p < NN)
        *reinterpret_cast<uint4*>(&outp[(size_t)(base + p) * HDIM + c * 8]) =
            *reinterpret_cast<const uint4*>(&O[p][c * 8]);
    }
    __syncthreads();
  }
}

// ---- MFMA small node projection (layers 1..3, K=32) ---------------------------------
__global__ __launch_bounds__(256) void k_node_projS_mfma(
    const float* __restrict__ x, const unsigned short* __restrict__ Wls,
    const unsigned short* __restrict__ Wrs, bf16* __restrict__ xl,
    bf16* __restrict__ xr) {
  __shared__ unsigned short A[MT][40];
  __shared__ unsigned short O[MT][264];
  int tid = threadIdx.x, l = tid & 63, w = tid >> 6;
  int lr = l & 15, lk = l >> 4;
  int base = blockIdx.x * MT;
  for (int t = tid; t < MT * 8; t += 256) {
    int p = t >> 3, q = t & 7;
    int row = base + p; if (row >= NN) row = NN - 1;
    float4 v = *reinterpret_cast<const float4*>(&x[(size_t)row * CH + q * 4]);
    unsigned short tmp[4] = {f2bs(v.x), f2bs(v.y), f2bs(v.z), f2bs(v.w)};
    *reinterpret_cast<uint2*>(&A[p][q * 4]) = *reinterpret_cast<const uint2*>(tmp);
  }
  __syncthreads();
  int j0 = w * 64;
#pragma unroll
  for (int mtx = 0; mtx < 2; ++mtx) {
    const unsigned short* Ws = (mtx == 0) ? Wls : Wrs;
    bf16* outp = (mtx == 0) ? xl : xr;
    f32x4 acc[4][4];
#pragma unroll
    for (int m = 0; m < 4; ++m)
#pragma unroll
      for (int n = 0; n < 4; ++n)
#pragma unroll
        for (int r = 0; r < 4; ++r) acc[m][n][r] = 0.f;
    bf16x8 a[4], b[4];
#pragma unroll
    for (int m = 0; m < 4; ++m)
      a[m] = *reinterpret_cast<const bf16x8*>(&A[m * 16 + lr][lk * 8]);
#pragma unroll
    for (int n = 0; n < 4; ++n) {
      int nt = (j0 >> 4) + n;
      b[n] = *reinterpret_cast<const bf16x8*>(Ws + ((size_t)nt * 64 + l) * 8);
    }
#pragma unroll
    for (int m = 0; m < 4; ++m)
#pragma unroll
      for (int n = 0; n < 4; ++n)
        acc[m][n] = __builtin_amdgcn_mfma_f32_16x16x32_bf16(a[m], b[n], acc[m][n], 0, 0, 0);
#pragma unroll
    for (int n = 0; n < 4; ++n)
#pragma unroll
      for (int m = 0; m < 4; ++m)
#pragma unroll
        for (int r = 0; r < 4; ++r)
          O[m * 16 + lk * 4 + r][j0 + n * 16 + lr] = f2bs(acc[m][n][r]);
    __syncthreads();
    for (int t = tid; t < MT * 32; t += 256) {
      int p = t >> 5, c = t & 31;
      if (base + p < NN)
        *reinterpret_cast<uint4*>(&outp[(size_t)(base + p) * HDIM + c * 8]) =
            *reinterpret_cast<const uint4*>(&O[p][c * 8]);
    }
    __syncthreads();
  }
}

// ---- MFMA SGFormer qkv --------------------------------------------------------------
__global__ __launch_bounds__(256) void k_sg_qkv_mfma(
    const float* __restrict__ x, const unsigned short* __restrict__ Wqs,
    const unsigned short* __restrict__ Wks, const unsigned short* __restrict__ Wvs,
    bf16* __restrict__ qs, bf16* __restrict__ ks, bf16* __restrict__ vv) {
  __shared__ unsigned short A[MT][264];
  __shared__ unsigned short O[MT][264];
  int tid = threadIdx.x, l = tid & 63, w = tid >> 6;
  int lr = l & 15, lk = l >> 4;
  int base = blockIdx.x * MT;
  for (int t = tid; t < MT * 64; t += 256) {
    int p = t >> 6, c = t & 63;
    int row = base + p; if (row >= NN) row = NN - 1;
    float4 v = *reinterpret_cast<const float4*>(&x[(size_t)row * HDIM + c * 4]);
    unsigned short tmp[4] = {f2bs(v.x), f2bs(v.y), f2bs(v.z), f2bs(v.w)};
    *reinterpret_cast<uint2*>(&A[p][c * 4]) = *reinterpret_cast<const uint2*>(tmp);
  }
  __syncthreads();
  int j0 = w * 64;
#pragma unroll
  for (int mtx = 0; mtx < 3; ++mtx) {
    const unsigned short* Ws = (mtx == 0) ? Wqs : (mtx == 1) ? Wks : Wvs;
    bf16* outp = (mtx == 0) ? qs : (mtx == 1) ? ks : vv;
    f32x4 acc[4][4];
#pragma unroll
    for (int m = 0; m < 4; ++m)
#pragma unroll
      for (int n = 0; n < 4; ++n)
#pragma unroll
        for (int r = 0; r < 4; ++r) acc[m][n][r] = 0.f;
    for (int k0 = 0; k0 < 8; ++k0) {
      bf16x8 a[4], b[4];
#pragma unroll
      for (int m = 0; m < 4; ++m)
        a[m] = *reinterpret_cast<const bf16x8*>(&A[m * 16 + lr][k0 * 32 + lk * 8]);
#pragma unroll
      for (int n = 0; n < 4; ++n) {
        int nt = (j0 >> 4) + n;
        b[n] = *reinterpret_cast<const bf16x8*>(Ws + ((size_t)(nt * 8 + k0) * 64 + l) * 8);
      }
#pragma unroll
      for (int m = 0; m < 4; ++m)
#pragma unroll
        for (int n = 0; n < 4; ++n)
          acc[m][n] = __builtin_amdgcn_mfma_f32_16x16x32_bf16(a[m], b[n], acc[m][n], 0, 0, 0);
    }
    if (mtx < 2) {
      float pa[4][4], pb[4][4];
#pragma unroll
      for (int m = 0; m < 4; ++m)
#pragma unroll
        for (int r = 0; r < 4; ++r) {
          pa[m][r] = acc[m][0][r] * acc[m][0][r] + acc[m][1][r] * acc[m][1][r];
          pb[m][r] = acc[m][2][r] * acc[m][2][r] + acc[m][3][r] * acc[m][3][r];
        }
#pragma unroll
      for (int off = 1; off < 16; off <<= 1) {
#pragma unroll
        for (int m = 0; m < 4; ++m)
#pragma unroll
          for (int r = 0; r < 4; ++r) {
            pa[m][r] += __shfl_xor(pa[m][r], off);
            pb[m][r] += __shfl_xor(pb[m][r], off);
          }
      }
#pragma unroll
      for (int m = 0; m < 4; ++m)
#pragma unroll
        for (int r = 0; r < 4; ++r) {
          float ra = 1.f / (sqrtf(pa[m][r]) + 1e-6f);
          float rb = 1.f / (sqrtf(pb[m][r]) + 1e-6f);
          acc[m][0][r] *= ra; acc[m][1][r] *= ra;
          acc[m][2][r] *= rb; acc[m][3][r] *= rb;
        }
    }
#pragma unroll
    for (int n = 0; n < 4; ++n)
#pragma unroll
      for (int m = 0; m < 4; ++m)
#pragma unroll
        for (int r = 0; r < 4; ++r)
          O[m * 16 + lk * 4 + r][j0 + n * 16 + lr] = f2bs(acc[m][n][r]);
    __syncthreads();
    for (int t = tid; t < MT * 32; t += 256) {
      int p = t >> 5, c = t & 31;
      if (base + p < NN)
        *reinterpret_cast<uint4*>(&outp[(size_t)(base + p) * HDIM + c * 8]) =
            *reinterpret_cast<const uint4*>(&O[p][c * 8]);
    }
    __syncthreads();
  }
}

// ---- sg_kv stage 1: per-block partials (NO atomics) ---------------------------------
__global__ void k_sg_kv1(const bf16* __restrict__ ks, const bf16* __restrict__ vv,
                         float* __restrict__ part) {
  int t = threadIdx.x;
  int h = t >> 5;
  float kvloc[CH];
  float ksl = 0.f;
#pragma unroll
  for (int d = 0; d < CH; ++d) kvloc[d] = 0.f;
  __shared__ float krow[HDIM], vrow[HDIM];
  for (int n = blockIdx.x; n < NN; n += KVB) {
    krow[t] = b2f(ks[(size_t)n * HDIM + t]);
    vrow[t] = b2f(vv[(size_t)n * HDIM + t]);
    __syncthreads();
    float kc = krow[t];
    ksl += kc;
#pragma unroll
    for (int d = 0; d < CH; ++d) kvloc[d] += kc * vrow[h * CH + d];
    __syncthreads();
  }
  float* dstp = part + (size_t)blockIdx.x * 8448;
#pragma unroll
  for (int d = 0; d < CH; d += 4)
    *reinterpret_cast<float4*>(&dstp[t * CH + d]) =
        *reinterpret_cast<const float4*>(&kvloc[d]);
  dstp[8192 + t] = ksl;
}

// ---- sg_kv stage 2: deterministic reduce over KVB partials --------------------------
__global__ void k_sg_kv2(const float* __restrict__ part, float* __restrict__ kv,
                         float* __restrict__ ksum) {
  int idx = blockIdx.x * 256 + threadIdx.x;
  if (idx >= 8448) return;
  float s = 0.f;
  for (int b = 0; b < KVB; ++b) s += part[(size_t)b * 8448 + idx];
  if (idx < 8192) kv[idx] = s;
  else ksum[idx - 8192] = s;
}

// ---- trans + combine + LN -> f32 out ------------------------------------------------
__global__ void k_sg_final(const bf16* __restrict__ qs, const bf16* __restrict__ vv,
                           const float* __restrict__ kv, const float* __restrict__ ksum,
                           const float* __restrict__ xg, const float* __restrict__ alphap,
                           const float* __restrict__ cng, const float* __restrict__ cnb,
                           float* __restrict__ out) {
  int t = threadIdx.x;
  int d = t & 31, sub = t >> 5;
  __shared__ float qrow[8][HDIM];
  __shared__ float crow[8][CH];
  int n = blockIdx.x * 8 + sub;
  for (int tt = t; tt < 8 * HDIM; tt += 256) {
    int p = tt >> 8, k = tt & 255;
    int n2 = blockIdx.x * 8 + p;
    if (n2 < NN) qrow[p][k] = b2f(qs[(size_t)n2 * HDIM + k]);
  }
  __syncthreads();
  float alpha = 1.f / (1.f + expf(-alphap[0]));
  const float Nf = (float)NN;
  float comb = 0.f;
  if (n < NN) {
    float acc = 0.f;
#pragma unroll
    for (int h = 0; h < NH; ++h) {
      float nm = 0.f, dp = 0.f;
#pragma unroll 8
      for (int c = 0; c < CH; ++c) {
        float qv = qrow[sub][h * CH + c];
        nm += qv * kv[(h * CH + c) * CH + d];
        dp += qv * ksum[h * CH + c];
      }
      nm += Nf * b2f(vv[(size_t)n * HDIM + h * CH + d]);
      acc += nm / (dp + Nf);
    }
    float trans = acc * (1.f / NH);
    comb = alpha * xg[(size_t)n * CH + d] + (1.f - alpha) * trans;
    crow[sub][d] = comb;
  }
  __syncthreads();
  if (n < NN) {
    float mu = 0.f;
#pragma unroll
    for (int k = 0; k < CH; ++k) mu += crow[sub][k];
    mu *= (1.f / CH);
    float var = 0.f;
#pragma unroll
    for (int k = 0; k < CH; ++k) { float dv = crow[sub][k] - mu; var += dv * dv; }
    var *= (1.f / CH);
    float o = (comb - mu) * rsqrtf(var + 1e-5f) * cng[d] + cnb[d];
    out[(size_t)n * CH + d] = o;
  }
}

extern "C" void kernel_launch(void* const* d_in, const int* in_sizes, int n_in,
                              void* d_out, int out_size, void* d_ws, size_t ws_size,
                              hipStream_t stream) {
  const float* mesh  = (const float*)d_in[0];
  const int*   eidx  = (const int*)d_in[1];
  const float* eattr = (const float*)d_in[2];
  const float* epW   = (const float*)d_in[3];
  const float* epb   = (const float*)d_in[4];
  const float* Wl0   = (const float*)d_in[5];
  const float* Wr0   = (const float*)d_in[6];
  const float* WlL   = (const float*)d_in[7];
  const float* WrL   = (const float*)d_in[8];
  const float* We0   = (const float*)d_in[9];
  const float* WeL   = (const float*)d_in[10];
  const float* att0  = (const float*)d_in[11];
  const float* attL  = (const float*)d_in[12];
  const float* Wres0 = (const float*)d_in[13];
  const float* WresL = (const float*)d_in[14];
  const float* bn0   = (const float*)d_in[15];
  const float* bnL   = (const float*)d_in[16];
  const float* Wu1_0 = (const float*)d_in[17];
  const float* Wu1L  = (const float*)d_in[18];
  const float* bu1_0 = (const float*)d_in[19];
  const float* bu1L  = (const float*)d_in[20];
  const float* Wu2_0 = (const float*)d_in[21];
  const float* Wu2L  = (const float*)d_in[22];
  const float* bu2_0 = (const float*)d_in[23];
  const float* bu2L  = (const float*)d_in[24];
  const float* lng   = (const float*)d_in[25];
  const float* lnb   = (const float*)d_in[26];
  const float* Wq    = (const float*)d_in[27];
  const float* Wk    = (const float*)d_in[28];
  const float* Wv    = (const float*)d_in[29];
  const float* alphap= (const float*)d_in[30];
  const float* cng   = (const float*)d_in[31];
  const float* cnb   = (const float*)d_in[32];

  const int* src = eidx;
  const int* dst = eidx + NE;

  char* base = (char*)d_ws;
  size_t o = 0;
  auto alloc = [&](size_t bytes) -> char* {
    o = (o + 255) & ~(size_t)255;
    char* p = base + o;
    o += bytes;
    return p;
  };
  bf16* e    = (bf16*)alloc((size_t)NE * HDIM * 2);
  bf16* xl   = (bf16*)alloc((size_t)NN * HDIM * 2);
  bf16* xr   = (bf16*)alloc((size_t)NN * HDIM * 2);
  bf16* vvb  = (bf16*)alloc((size_t)NN * HDIM * 2);
  float* sxc = (float*)alloc((size_t)NE * NH * 4);    // exp(scores), CSR-ordered
  float* xa  = (float*)alloc((size_t)NN * CH * 4);
  float* xb  = (float*)alloc((size_t)NN * CH * 4);
  float* xc  = (float*)alloc((size_t)NN * CH * 4);
  float* kv  = (float*)alloc(NH * CH * CH * 4);
  float* ksum= (float*)alloc(NH * CH * 4);
  float* kvpart = (float*)alloc((size_t)KVB * 8448 * 4);   // 17.3 MB
  unsigned short* w1s = (unsigned short*)alloc((size_t)3 * 320 * 256 * 2);
  unsigned short* w2s = (unsigned short*)alloc((size_t)3 * 256 * 256 * 2);
  unsigned short* wall= (unsigned short*)alloc((size_t)9 * 65536 * 2);
  unsigned short* w32s= (unsigned short*)alloc((size_t)6 * 32 * 256 * 2);
  unsigned short* wep = (unsigned short*)alloc((size_t)SWZ_N4 * 2);
  int* cnt    = (int*)alloc((size_t)NN * 4);
  int* rowptr = (int*)alloc((size_t)(NN + 1) * 4);
  int* cursor = (int*)alloc((size_t)NN * 4);
  int* csrsrc = (int*)alloc((size_t)NE * 4);
  int* pos    = (int*)alloc((size_t)NE * 4);
  if (ws_size < o) return;   // fail cleanly if ws too small

  // fused pre-pass: all weight swizzles (incl. epW) + cnt zeroing in ONE launch
  SwzP P;
  P.We0 = We0; P.WeL = WeL; P.Wl0 = Wl0; P.Wr0 = Wr0; P.Wq = Wq; P.Wk = Wk; P.Wv = Wv;
  P.Wu1_0 = Wu1_0; P.Wu1L = Wu1L; P.Wu2_0 = Wu2_0; P.Wu2L = Wu2L;
  P.WlL = WlL; P.WrL = WrL; P.epW = epW;
  P.wall = wall; P.w1s = w1s; P.w2s = w2s; P.w32s = w32s; P.wep = wep; P.cnt = cnt;
  int swz_total = SWZ_NW + SWZ_N1 + SWZ_N2 + SWZ_N3 + SWZ_N4 + NN;
  k_swz_fused<<<(swz_total + 255) / 256, 256, 0, stream>>>(P);

  // CSR build (graph constant across layers); pos[e] = CSR slot of edge e
  k_csr_count<<<(NE + 255) / 256, 256, 0, stream>>>(dst, cnt);
  k_csr_scan<<<1, 256, 0, stream>>>(cnt, rowptr, cursor);
  k_csr_fill<<<(NE + 255) / 256, 256, 0, stream>>>(src, dst, cursor, csrsrc, pos);

  k_edge_proj_mfma<<<NE / MT, 512, 0, stream>>>(eattr, wep, epb, e);

  const float* xin = mesh;
  float* post = xb;
  for (int l = 0; l < 4; ++l) {
    const float *att_p, *Wres_p, *bn_p, *bu1_p, *bu2_p;
    if (l == 0) {
      att_p = att0; Wres_p = Wres0; bn_p = bn0; bu1_p = bu1_0; bu2_p = bu2_0;
    } else {
      int i = l - 1;
      att_p = attL + (size_t)i * HDIM;
      Wres_p = WresL + (size_t)i * CH * CH;
      bn_p = bnL + (size_t)i * CH;
      bu1_p = bu1L + (size_t)i * HDIM;
      bu2_p = bu2L + (size_t)i * HDIM;
    }

    if (l == 0)
      k_node_proj0_mfma<<<(NN + MT - 1) / MT, 256, 0, stream>>>(
          mesh, wall + (size_t)4 * 65536, wall + (size_t)5 * 65536, xl, xr);
    else
      k_node_projS_mfma<<<(NN + MT - 1) / MT, 256, 0, stream>>>(
          xin, w32s + (size_t)((l - 1) * 2 + 0) * 8192,
          w32s + (size_t)((l - 1) * 2 + 1) * 8192, xl, xr);

    k_edge_score_mfma<<<NE / MT, 512, 0, stream>>>(e, wall + (size_t)l * 65536,
                                                   xl, xr, att_p, src, dst, pos, sxc);

    if (l == 0)
      k_gat_out<HDIM, true><<<NN, 256, 0, stream>>>(rowptr, csrsrc, sxc, xl, xin, Wres_p,
                                                    bn_p, lng, lnb, xa, post);
    else if (l < 3)
      k_gat_out<CH, true><<<NN, 256, 0, stream>>>(rowptr, csrsrc, sxc, xl, xin, Wres_p,
                                                  bn_p, lng + (size_t)l * CH,
                                                  lnb + (size_t)l * CH, xa, post);
    else
      k_gat_out<CH, false><<<NN, 256, 0, stream>>>(rowptr, csrsrc, sxc, xl, xin, Wres_p,
                                                   bn_p, nullptr, nullptr, xa, nullptr);

    if (l < 3)
      k_edge_mlp_mfma<<<NE / MT, 512, 0, stream>>>(e, xa, src, dst,
                                                   w1s + (size_t)l * 320 * 256, bu1_p,
                                                   w2s + (size_t)l * 256 * 256, bu2_p);

    xin = post;
    post = (post == xb) ? xc : xb;
  }
  // final GAT output (no LN) is in xa

  k_sg_qkv_mfma<<<(NN + MT - 1) / MT, 256, 0, stream>>>(
      mesh, wall + (size_t)6 * 65536, wall + (size_t)7 * 65536,
      wall + (size_t)8 * 65536, xl, xr, vvb);
  k_sg_kv1<<<KVB, 256, 0, stream>>>(xr, vvb, kvpart);
  k_sg_kv2<<<33, 256, 0, stream>>>(kvpart, kv, ksum);
  k_sg_final<<<(NN + 7) / 8, 256, 0, stream>>>(xl, vvb, kv, ksum, xa, alphap, cng, cnb,
                                               (float*)d_out);
}

// Round 17
// 1424.022 us; speedup vs baseline: 1.0203x; 1.0203x over previous
//
#include <hip/hip_runtime.h>
#include <hip/hip_bf16.h>
#include <math.h>

typedef __hip_bfloat16 bf16;
typedef __attribute__((ext_vector_type(8))) __bf16 bf16x8;
typedef __attribute__((ext_vector_type(4))) float f32x4;

#define NN 40962
#define NE 245760
#define HDIM 256
#define NH 8
#define CH 32

#define MT 64     // rows per block in MFMA kernels
#define KVB 512   // stage-1 blocks for sg_kv partial reduction

__device__ __forceinline__ float b2f(bf16 v) { return __bfloat162float(v); }
__device__ __forceinline__ bf16 f2b(float v) { return __float2bfloat16(v); }
__device__ __forceinline__ unsigned short f2bs(float v) {
  bf16 b = __float2bfloat16(v);
  return __builtin_bit_cast(unsigned short, b);
}
__device__ __forceinline__ float bs2f(unsigned short u) {
  return __bfloat162float(__builtin_bit_cast(bf16, u));
}

// gelu (tanh form) with native exp2: tanh(g) = (e^{2g}-1)/(e^{2g}+1)
__device__ __forceinline__ float fast_gelu(float x) {
  float x2 = x * x;
  float g = x * (0.7978845608028654f + 0.0356774081f * x2);
  float y = fminf(g * 2.885390081777927f, 60.f);   // 2*log2(e)*g, clamped
  float t = exp2f(y);
  float th = (t - 1.f) * __builtin_amdgcn_rcpf(t + 1.f);
  return 0.5f * x * (1.f + th);
}

// ---- MFMA edge input projection: e = attr @ epW + epb (K=16 zero-padded to 32) ------
__global__ __launch_bounds__(512) void k_edge_proj_mfma(
    const float* __restrict__ attr, const unsigned short* __restrict__ Weps,
    const float* __restrict__ bias, bf16* __restrict__ e) {
  __shared__ unsigned short At[MT][40];    // 64 x 32 (cols 16..31 zero) + pad
  __shared__ unsigned short O[MT][264];
  int tid = threadIdx.x, l = tid & 63, w = tid >> 6;
  int lr = l & 15, lk = l >> 4;
  int base = blockIdx.x * MT;              // NE % 64 == 0
  {
    int p = tid >> 3, q = tid & 7;         // 512 threads = 64 x 8 exactly
    if (q < 4) {
      float4 v = *reinterpret_cast<const float4*>(&attr[(size_t)(base + p) * 16 + q * 4]);
      unsigned short tmp[4] = {f2bs(v.x), f2bs(v.y), f2bs(v.z), f2bs(v.w)};
      *reinterpret_cast<uint2*>(&At[p][q * 4]) = *reinterpret_cast<const uint2*>(tmp);
    } else {
      unsigned short z[4] = {0, 0, 0, 0};
      *reinterpret_cast<uint2*>(&At[p][q * 4]) = *reinterpret_cast<const uint2*>(z);
    }
  }
  __syncthreads();

  int j0 = w * 32;
  f32x4 acc[4][2];
#pragma unroll
  for (int m = 0; m < 4; ++m)
#pragma unroll
    for (int n = 0; n < 2; ++n)
#pragma unroll
      for (int r = 0; r < 4; ++r) acc[m][n][r] = 0.f;
  {
    bf16x8 a[4], b[2];
#pragma unroll
    for (int m = 0; m < 4; ++m)
      a[m] = *reinterpret_cast<const bf16x8*>(&At[m * 16 + lr][lk * 8]);
#pragma unroll
    for (int n = 0; n < 2; ++n) {
      int nt = w * 2 + n;
      b[n] = *reinterpret_cast<const bf16x8*>(Weps + ((size_t)nt * 64 + l) * 8);
    }
#pragma unroll
    for (int m = 0; m < 4; ++m)
#pragma unroll
      for (int n = 0; n < 2; ++n)
        acc[m][n] = __builtin_amdgcn_mfma_f32_16x16x32_bf16(a[m], b[n], acc[m][n], 0, 0, 0);
  }
#pragma unroll
  for (int n = 0; n < 2; ++n) {
    int col = j0 + n * 16 + lr;
    float bv = bias[col];
#pragma unroll
    for (int m = 0; m < 4; ++m)
#pragma unroll
      for (int r = 0; r < 4; ++r)
        O[m * 16 + lk * 4 + r][col] = f2bs(acc[m][n][r] + bv);
  }
  __syncthreads();
  for (int t = tid; t < MT * 32; t += 512) {
    int p = t >> 5, c = t & 31;
    *reinterpret_cast<uint4*>(&e[(size_t)(base + p) * HDIM + c * 8]) =
        *reinterpret_cast<const uint4*>(&O[p][c * 8]);
  }
}

// ---- CSR build: count, scan(+cursor), fill (records pos[e] = CSR slot) --------------
__global__ void k_csr_count(const int* __restrict__ dst, int* __restrict__ cnt) {
  int e = blockIdx.x * 256 + threadIdx.x;
  if (e < NE) atomicAdd(&cnt[dst[e]], 1);
}
__global__ void k_csr_scan(const int* __restrict__ cnt, int* __restrict__ rowptr,
                           int* __restrict__ cursor) {
  __shared__ int part[256];
  __shared__ int tot;
  int t = threadIdx.x;
  const int CHUNK = (NN + 255) / 256;
  int lo = t * CHUNK, hi = lo + CHUNK; if (hi > NN) hi = NN; if (lo > NN) lo = NN;
  int s = 0;
  for (int i = lo; i < hi; ++i) s += cnt[i];
  part[t] = s;
  __syncthreads();
  if (t == 0) {
    int run = 0;
    for (int i = 0; i < 256; ++i) { int v = part[i]; part[i] = run; run += v; }
    tot = run;
  }
  __syncthreads();
  int run = part[t];
  for (int i = lo; i < hi; ++i) { rowptr[i] = run; cursor[i] = run; run += cnt[i]; }
  if (t == 0) rowptr[NN] = tot;
}
__global__ void k_csr_fill(const int* __restrict__ src, const int* __restrict__ dst,
                           int* __restrict__ cursor, int* __restrict__ csrsrc,
                           int* __restrict__ pos) {
  int e = blockIdx.x * 256 + threadIdx.x;
  if (e >= NE) return;
  int p = atomicAdd(&cursor[dst[e]], 1);
  csrsrc[p] = src[e];
  pos[e] = p;
}

// ---- fused weight swizzle (all matrices) + cnt zeroing ------------------------------
struct SwzP {
  const float *We0, *WeL, *Wl0, *Wr0, *Wq, *Wk, *Wv;
  const float *Wu1_0, *Wu1L, *Wu2_0, *Wu2L, *WlL, *WrL, *epW;
  unsigned short *wall, *w1s, *w2s, *w32s, *wep;
  int* cnt;
};
__device__ __forceinline__ void swz1(const float* __restrict__ W,
                                     unsigned short* __restrict__ out, int t, int Kdiv32) {
  int i = t & 7, l = (t >> 3) & 63;
  int k0 = (t >> 9) % Kdiv32;
  int n0 = t / (512 * Kdiv32);
  int k = k0 * 32 + (l >> 4) * 8 + i;
  int n = n0 * 16 + (l & 15);
  out[t] = f2bs(W[k * 256 + n]);
}
#define SWZ_NW (9 * 65536)
#define SWZ_N1 (3 * 81920)
#define SWZ_N2 (3 * 65536)
#define SWZ_N3 (6 * 8192)
#define SWZ_N4 8192
__global__ void k_swz_fused(SwzP P) {
  int gid = blockIdx.x * 256 + threadIdx.x;
  if (gid < SWZ_NW) {
    int mat = gid >> 16, t = gid & 65535;
    const float* W;
    switch (mat) {
      case 0: W = P.We0; break;
      case 1: W = P.WeL; break;
      case 2: W = P.WeL + 65536; break;
      case 3: W = P.WeL + 131072; break;
      case 4: W = P.Wl0; break;
      case 5: W = P.Wr0; break;
      case 6: W = P.Wq; break;
      case 7: W = P.Wk; break;
      default: W = P.Wv; break;
    }
    swz1(W, P.wall + (size_t)mat * 65536, t, 8);
  } else if (gid < SWZ_NW + SWZ_N1) {
    int idx = gid - SWZ_NW;
    int mat = idx / 81920, t = idx % 81920;
    const float* W = (mat == 0) ? P.Wu1_0 : P.Wu1L + (size_t)(mat - 1) * 81920;
    swz1(W, P.w1s + (size_t)mat * 81920, t, 10);
  } else if (gid < SWZ_NW + SWZ_N1 + SWZ_N2) {
    int idx = gid - SWZ_NW - SWZ_N1;
    int mat = idx >> 16, t = idx & 65535;
    const float* W = (mat == 0) ? P.Wu2_0 : P.Wu2L + (size_t)(mat - 1) * 65536;
    swz1(W, P.w2s + (size_t)mat * 65536, t, 8);
  } else if (gid < SWZ_NW + SWZ_N1 + SWZ_N2 + SWZ_N3) {
    int idx = gid - SWZ_NW - SWZ_N1 - SWZ_N2;
    int mat = idx >> 13, t = idx & 8191;
    int i = mat >> 1;
    const float* W = (mat & 1) ? P.WrL + (size_t)i * 8192 : P.WlL + (size_t)i * 8192;
    swz1(W, P.w32s + (size_t)mat * 8192, t, 1);
  } else if (gid < SWZ_NW + SWZ_N1 + SWZ_N2 + SWZ_N3 + SWZ_N4) {
    // epW [16][256] zero-padded to K=32 fragment layout
    int t = gid - (SWZ_NW + SWZ_N1 + SWZ_N2 + SWZ_N3);
    int i = t & 7, l = (t >> 3) & 63;
    int n0 = t >> 9;
    int k = (l >> 4) * 8 + i;
    int n = n0 * 16 + (l & 15);
    P.wep[t] = (k < 16) ? f2bs(P.epW[k * 256 + n]) : (unsigned short)0;
  } else {
    int i = gid - (SWZ_NW + SWZ_N1 + SWZ_N2 + SWZ_N3 + SWZ_N4);
    if (i < NN) P.cnt[i] = 0;
  }
}

// ---- MFMA edge score -> writes sxc[pos[e]*8+h] = exp(s)  (CSR-ordered) --------------
__global__ __launch_bounds__(512) void k_edge_score_mfma(
    const bf16* __restrict__ e, const unsigned short* __restrict__ Wes,
    const bf16* __restrict__ xl, const bf16* __restrict__ xr,
    const float* __restrict__ att, const int* __restrict__ src,
    const int* __restrict__ dst, const int* __restrict__ pos,
    float* __restrict__ sxc) {
  __shared__ unsigned short Ae[MT][264];   // e-tile, then reused as scoreboard
  __shared__ float attS[HDIM];
  __shared__ int sidx[MT], didx[MT];
  int tid = threadIdx.x, l = tid & 63, w = tid >> 6;
  int lr = l & 15, lk = l >> 4;
  int base = blockIdx.x * MT;
  if (tid < HDIM) attS[tid] = att[tid];
  if (tid < MT) sidx[tid] = src[base + tid];
  else if (tid < 2 * MT) didx[tid - MT] = dst[base + tid - MT];
  for (int t = tid; t < MT * 32; t += 512) {
    int p = t >> 5, c = t & 31;
    *reinterpret_cast<uint4*>(&Ae[p][c * 8]) =
        *reinterpret_cast<const uint4*>(&e[(size_t)(base + p) * HDIM + c * 8]);
  }
  __syncthreads();

  f32x4 acc[4][2];
#pragma unroll
  for (int m = 0; m < 4; ++m)
#pragma unroll
    for (int n = 0; n < 2; ++n)
#pragma unroll
      for (int r = 0; r < 4; ++r) acc[m][n][r] = 0.f;
  for (int k0 = 0; k0 < 8; ++k0) {
    bf16x8 a[4], b[2];
#pragma unroll
    for (int m = 0; m < 4; ++m)
      a[m] = *reinterpret_cast<const bf16x8*>(&Ae[m * 16 + lr][k0 * 32 + lk * 8]);
#pragma unroll
    for (int n = 0; n < 2; ++n) {
      int nt = w * 2 + n;
      b[n] = *reinterpret_cast<const bf16x8*>(Wes + ((size_t)(nt * 8 + k0) * 64 + l) * 8);
    }
#pragma unroll
    for (int m = 0; m < 4; ++m)
#pragma unroll
      for (int n = 0; n < 2; ++n)
        acc[m][n] = __builtin_amdgcn_mfma_f32_16x16x32_bf16(a[m], b[n], acc[m][n], 0, 0, 0);
  }
  __syncthreads();   // all Ae reads complete before scoreboard overwrite

  // epilogue: xl/xr read directly from global (L2-hot), scoreboard into Ae alias
#pragma unroll
  for (int n = 0; n < 2; ++n) {
    int col = w * 32 + n * 16 + lr;
    float av = attS[col];
#pragma unroll
    for (int m = 0; m < 4; ++m)
#pragma unroll
      for (int r = 0; r < 4; ++r) {
        int row = m * 16 + lk * 4 + r;
        float xs = b2f(xl[(size_t)sidx[row] * HDIM + col]) +
                   b2f(xr[(size_t)didx[row] * HDIM + col]);
        float mm = acc[m][n][r] + xs;
        mm = (mm > 0.f) ? mm : 0.2f * mm;
        Ae[row][col] = f2bs(mm * av);
      }
  }
  __syncthreads();
  for (int pair = tid; pair < MT * NH; pair += 512) {
    int ed = pair >> 3, h = pair & 7;
    float s = 0.f;
#pragma unroll
    for (int c = 0; c < CH; ++c) s += bs2f(Ae[ed][h * CH + c]);
    sxc[(size_t)pos[base + ed] * NH + h] = expf(s);
  }
}

// ---- fused CSR aggregate + node output + optional LN --------------------------------
// sxc is CSR-ordered: node n's ex values are contiguous at [rowptr[n]*8, rowptr[n+1]*8)
#define GCHUNK 64
template <int ID, bool LN>
__global__ __launch_bounds__(256) void k_gat_out(
    const int* __restrict__ rowptr, const int* __restrict__ csrsrc,
    const float* __restrict__ sxc, const bf16* __restrict__ xl,
    const float* __restrict__ x, const float* __restrict__ Wres,
    const float* __restrict__ bn, const float* __restrict__ lng,
    const float* __restrict__ lnb, float* __restrict__ xpre,
    float* __restrict__ xpost) {
  int n = blockIdx.x;
  int j = threadIdx.x;
  int h = j >> 5, c = j & 31;
  int p0 = rowptr[n], p1 = rowptr[n + 1];
  __shared__ int srcS[GCHUNK];
  __shared__ float exS[GCHUNK * NH];
  float a = 0.f, dsum = 0.f;
  for (int pb = p0; pb < p1; pb += GCHUNK) {
    int chunk = p1 - pb; if (chunk > GCHUNK) chunk = GCHUNK;
    if (j < chunk) srcS[j] = csrsrc[pb + j];
    for (int t = j; t < chunk * NH; t += 256) exS[t] = sxc[(size_t)pb * NH + t];
    __syncthreads();
    int i = 0;
    for (; i + 4 <= chunk; i += 4) {
      float e0 = exS[(i + 0) * NH + h], e1 = exS[(i + 1) * NH + h];
      float e2 = exS[(i + 2) * NH + h], e3 = exS[(i + 3) * NH + h];
      float x0 = b2f(xl[(size_t)srcS[i + 0] * HDIM + j]);
      float x1 = b2f(xl[(size_t)srcS[i + 1] * HDIM + j]);
      float x2 = b2f(xl[(size_t)srcS[i + 2] * HDIM + j]);
      float x3 = b2f(xl[(size_t)srcS[i + 3] * HDIM + j]);
      a += e0 * x0 + e1 * x1 + e2 * x2 + e3 * x3;
      dsum += e0 + e1 + e2 + e3;
    }
    for (; i < chunk; ++i) {
      float ev = exS[i * NH + h];
      a += ev * b2f(xl[(size_t)srcS[i] * HDIM + j]);
      dsum += ev;
    }
    __syncthreads();
  }
  __shared__ float oh[HDIM];
  __shared__ float rs[NH][CH];
  __shared__ float oc[CH + 1];
  oh[j] = a / (dsum + 1e-16f);
  const int KS = ID / NH;
  float r = 0.f;
  for (int k = h * KS; k < (h + 1) * KS; ++k)
    r += x[(size_t)n * ID + k] * Wres[k * CH + c];
  rs[h][c] = r;
  __syncthreads();
  if (j < CH) {
    float o = 0.f;
#pragma unroll
    for (int hh = 0; hh < NH; ++hh) o += oh[hh * CH + j];
    o *= (1.f / NH);
    float rr = 0.f;
#pragma unroll
    for (int hh = 0; hh < NH; ++hh) rr += rs[hh][j];
    o += rr + bn[j];
    xpre[(size_t)n * CH + j] = o;
    oc[j] = o;
  }
  __syncthreads();
  if (LN && j < CH) {
    float mu = 0.f;
#pragma unroll
    for (int k = 0; k < CH; ++k) mu += oc[k];
    mu *= (1.f / CH);
    float var = 0.f;
#pragma unroll
    for (int k = 0; k < CH; ++k) { float d = oc[k] - mu; var += d * d; }
    var *= (1.f / CH);
    xpost[(size_t)n * CH + j] = (oc[j] - mu) * rsqrtf(var + 1e-5f) * lng[j] + lnb[j];
  }
}

// ---- MFMA residual edge MLP (8 waves, single aliased 42KB LDS buffer) ---------------
__global__ __launch_bounds__(512) void k_edge_mlp_mfma(
    bf16* __restrict__ e, const float* __restrict__ xo,
    const int* __restrict__ src, const int* __restrict__ dst,
    const unsigned short* __restrict__ W1s, const float* __restrict__ bu1,
    const unsigned short* __restrict__ W2s, const float* __restrict__ bu2) {
  __shared__ unsigned short buf[MT][328];   // A1 (xo|e), then gelu(h1), then delta
  __shared__ int sidx[MT], didx[MT];
  int tid = threadIdx.x;
  int l = tid & 63;
  int w = tid >> 6;
  int base = blockIdx.x * MT;
  int lr = l & 15;
  int lk = l >> 4;

  if (tid < MT) sidx[tid] = src[base + tid];
  else if (tid < 2 * MT) didx[tid - MT] = dst[base + tid - MT];
  __syncthreads();

  for (int t = tid; t < MT * 32; t += 512) {
    int p = t >> 5, cc = t & 31;
    uint4 v = *reinterpret_cast<const uint4*>(&e[(size_t)(base + p) * HDIM + cc * 8]);
    *reinterpret_cast<uint4*>(&buf[p][64 + cc * 8]) = v;
  }
  for (int t = tid; t < MT * 64; t += 512) {
    int p = t >> 6, c = t & 63;
    float v = (c < CH) ? xo[(size_t)sidx[p] * CH + c]
                       : xo[(size_t)didx[p] * CH + (c - CH)];
    buf[p][c] = f2bs(v);
  }
  __syncthreads();

  int j0 = w * 32;

  f32x4 acc[4][2];
#pragma unroll
  for (int m = 0; m < 4; ++m)
#pragma unroll
    for (int n = 0; n < 2; ++n)
#pragma unroll
      for (int r = 0; r < 4; ++r) acc[m][n][r] = 0.f;

  for (int k0 = 0; k0 < 10; ++k0) {
    bf16x8 a[4], b[2];
#pragma unroll
    for (int m = 0; m < 4; ++m)
      a[m] = *reinterpret_cast<const bf16x8*>(&buf[m * 16 + lr][k0 * 32 + lk * 8]);
#pragma unroll
    for (int n = 0; n < 2; ++n) {
      int nt = w * 2 + n;
      b[n] = *reinterpret_cast<const bf16x8*>(W1s + ((size_t)(nt * 10 + k0) * 64 + l) * 8);
    }
#pragma unroll
    for (int m = 0; m < 4; ++m)
#pragma unroll
      for (int n = 0; n < 2; ++n)
        acc[m][n] = __builtin_amdgcn_mfma_f32_16x16x32_bf16(a[m], b[n], acc[m][n], 0, 0, 0);
  }
  __syncthreads();   // all A1 reads complete before overwrite

  // gelu(h1 + bu1) -> buf alias (cols 0..255)
#pragma unroll
  for (int n = 0; n < 2; ++n) {
    float bv = bu1[j0 + n * 16 + lr];
#pragma unroll
    for (int m = 0; m < 4; ++m)
#pragma unroll
      for (int r = 0; r < 4; ++r) {
        float g = fast_gelu(acc[m][n][r] + bv);
        buf[m * 16 + lk * 4 + r][j0 + n * 16 + lr] = f2bs(g);
      }
  }
  __syncthreads();

#pragma unroll
  for (int m = 0; m < 4; ++m)
#pragma unroll
    for (int n = 0; n < 2; ++n)
#pragma unroll
      for (int r = 0; r < 4; ++r) acc[m][n][r] = 0.f;

  for (int k0 = 0; k0 < 8; ++k0) {
    bf16x8 a[4], b[2];
#pragma unroll
    for (int m = 0; m < 4; ++m)
      a[m] = *reinterpret_cast<const bf16x8*>(&buf[m * 16 + lr][k0 * 32 + lk * 8]);
#pragma unroll
    for (int n = 0; n < 2; ++n) {
      int nt = w * 2 + n;
      b[n] = *reinterpret_cast<const bf16x8*>(W2s + ((size_t)(nt * 8 + k0) * 64 + l) * 8);
    }
#pragma unroll
    for (int m = 0; m < 4; ++m)
#pragma unroll
      for (int n = 0; n < 2; ++n)
        acc[m][n] = __builtin_amdgcn_mfma_f32_16x16x32_bf16(a[m], b[n], acc[m][n], 0, 0, 0);
  }
  __syncthreads();   // all gelu reads done before delta overwrite

  // delta = acc + bu2 -> buf alias
#pragma unroll
  for (int n = 0; n < 2; ++n) {
    int col = j0 + n * 16 + lr;
    float bv = bu2[col];
#pragma unroll
    for (int m = 0; m < 4; ++m)
#pragma unroll
      for (int r = 0; r < 4; ++r)
        buf[m * 16 + lk * 4 + r][col] = f2bs(acc[m][n][r] + bv);
  }
  __syncthreads();

  // store: e_new = e_old (global re-read, L2-hot) + delta
  for (int t = tid; t < MT * 32; t += 512) {
    int p = t >> 5, cc = t & 31;
    uint4 dv = *reinterpret_cast<const uint4*>(&buf[p][cc * 8]);
    uint4 ev = *reinterpret_cast<const uint4*>(&e[(size_t)(base + p) * HDIM + cc * 8]);
    const unsigned short* dd = (const unsigned short*)&dv;
    const unsigned short* ee = (const unsigned short*)&ev;
    unsigned short ov[8];
#pragma unroll
    for (int i = 0; i < 8; ++i) ov[i] = f2bs(bs2f(ee[i]) + bs2f(dd[i]));
    *reinterpret_cast<uint4*>(&e[(size_t)(base + p) * HDIM + cc * 8]) =
        *reinterpret_cast<const uint4*>(ov);
  }
}

// ---- MFMA layer-0 node projection ---------------------------------------------------
__global__ __launch_bounds__(256) void k_node_proj0_mfma(
    const float* __restrict__ x, const unsigned short* __restrict__ Wls,
    const unsigned short* __restrict__ Wrs, bf16* __restrict__ xl,
    bf16* __restrict__ xr) {
  __shared__ unsigned short A[MT][264];
  __shared__ unsigned short O[MT][264];
  int tid = threadIdx.x, l = tid & 63, w = tid >> 6;
  int lr = l & 15, lk = l >> 4;
  int base = blockIdx.x * MT;
  for (int t = tid; t < MT * 64; t += 256) {
    int p = t >> 6, c = t & 63;
    int row = base + p; if (row >= NN) row = NN - 1;
    float4 v = *reinterpret_cast<const float4*>(&x[(size_t)row * HDIM + c * 4]);
    unsigned short tmp[4] = {f2bs(v.x), f2bs(v.y), f2bs(v.z), f2bs(v.w)};
    *reinterpret_cast<uint2*>(&A[p][c * 4]) = *reinterpret_cast<const uint2*>(tmp);
  }
  __syncthreads();
  int j0 = w * 64;
#pragma unroll
  for (int mtx = 0; mtx < 2; ++mtx) {
    const unsigned short* Ws = (mtx == 0) ? Wls : Wrs;
    bf16* outp = (mtx == 0) ? xl : xr;
    f32x4 acc[4][4];
#pragma unroll
    for (int m = 0; m < 4; ++m)
#pragma unroll
      for (int n = 0; n < 4; ++n)
#pragma unroll
        for (int r = 0; r < 4; ++r) acc[m][n][r] = 0.f;
    for (int k0 = 0; k0 < 8; ++k0) {
      bf16x8 a[4], b[4];
#pragma unroll
      for (int m = 0; m < 4; ++m)
        a[m] = *reinterpret_cast<const bf16x8*>(&A[m * 16 + lr][k0 * 32 + lk * 8]);
#pragma unroll
      for (int n = 0; n < 4; ++n) {
        int nt = (j0 >> 4) + n;
        b[n] = *reinterpret_cast<const bf16x8*>(Ws + ((size_t)(nt * 8 + k0) * 64 + l) * 8);
      }
#pragma unroll
      for (int m = 0; m < 4; ++m)
#pragma unroll
        for (int n = 0; n < 4; ++n)
          acc[m][n] = __builtin_amdgcn_mfma_f32_16x16x32_bf16(a[m], b[n], acc[m][n], 0, 0, 0);
    }
#pragma unroll
    for (int n = 0; n < 4; ++n)
#pragma unroll
      for (int m = 0; m < 4; ++m)
#pragma unroll
        for (int r = 0; r < 4; ++r)
          O[m * 16 + lk * 4 + r][j0 + n * 16 + lr] = f2bs(acc[m][n][r]);
    __syncthreads();
    for (int t = tid; t < MT * 32; t += 256) {
      int p = t >> 5, c = t & 31;
      if (base + p < NN)
        *reinterpret_cast<uint4*>(&outp[(size_t)(base + p) * HDIM + c * 8]) =
            *reinterpret_cast<const uint4*>(&O[p][c * 8]);
    }
    __syncthreads();
  }
}

// ---- MFMA small node projection (layers 1..3, K=32) ---------------------------------
__global__ __launch_bounds__(256) void k_node_projS_mfma(
    const float* __restrict__ x, const unsigned short* __restrict__ Wls,
    const unsigned short* __restrict__ Wrs, bf16* __restrict__ xl,
    bf16* __restrict__ xr) {
  __shared__ unsigned short A[MT][40];
  __shared__ unsigned short O[MT][264];
  int tid = threadIdx.x, l = tid & 63, w = tid >> 6;
  int lr = l & 15, lk = l >> 4;
  int base = blockIdx.x * MT;
  for (int t = tid; t < MT * 8; t += 256) {
    int p = t >> 3, q = t & 7;
    int row = base + p; if (row >= NN) row = NN - 1;
    float4 v = *reinterpret_cast<const float4*>(&x[(size_t)row * CH + q * 4]);
    unsigned short tmp[4] = {f2bs(v.x), f2bs(v.y), f2bs(v.z), f2bs(v.w)};
    *reinterpret_cast<uint2*>(&A[p][q * 4]) = *reinterpret_cast<const uint2*>(tmp);
  }
  __syncthreads();
  int j0 = w * 64;
#pragma unroll
  for (int mtx = 0; mtx < 2; ++mtx) {
    const unsigned short* Ws = (mtx == 0) ? Wls : Wrs;
    bf16* outp = (mtx == 0) ? xl : xr;
    f32x4 acc[4][4];
#pragma unroll
    for (int m = 0; m < 4; ++m)
#pragma unroll
      for (int n = 0; n < 4; ++n)
#pragma unroll
        for (int r = 0; r < 4; ++r) acc[m][n][r] = 0.f;
    bf16x8 a[4], b[4];
#pragma unroll
    for (int m = 0; m < 4; ++m)
      a[m] = *reinterpret_cast<const bf16x8*>(&A[m * 16 + lr][lk * 8]);
#pragma unroll
    for (int n = 0; n < 4; ++n) {
      int nt = (j0 >> 4) + n;
      b[n] = *reinterpret_cast<const bf16x8*>(Ws + ((size_t)nt * 64 + l) * 8);
    }
#pragma unroll
    for (int m = 0; m < 4; ++m)
#pragma unroll
      for (int n = 0; n < 4; ++n)
        acc[m][n] = __builtin_amdgcn_mfma_f32_16x16x32_bf16(a[m], b[n], acc[m][n], 0, 0, 0);
#pragma unroll
    for (int n = 0; n < 4; ++n)
#pragma unroll
      for (int m = 0; m < 4; ++m)
#pragma unroll
        for (int r = 0; r < 4; ++r)
          O[m * 16 + lk * 4 + r][j0 + n * 16 + lr] = f2bs(acc[m][n][r]);
    __syncthreads();
    for (int t = tid; t < MT * 32; t += 256) {
      int p = t >> 5, c = t & 31;
      if (base + p < NN)
        *reinterpret_cast<uint4*>(&outp[(size_t)(base + p) * HDIM + c * 8]) =
            *reinterpret_cast<const uint4*>(&O[p][c * 8]);
    }
    __syncthreads();
  }
}

// ---- MFMA SGFormer qkv --------------------------------------------------------------
__global__ __launch_bounds__(256) void k_sg_qkv_mfma(
    const float* __restrict__ x, const unsigned short* __restrict__ Wqs,
    const unsigned short* __restrict__ Wks, const unsigned short* __restrict__ Wvs,
    bf16* __restrict__ qs, bf16* __restrict__ ks, bf16* __restrict__ vv) {
  __shared__ unsigned short A[MT][264];
  __shared__ unsigned short O[MT][264];
  int tid = threadIdx.x, l = tid & 63, w = tid >> 6;
  int lr = l & 15, lk = l >> 4;
  int base = blockIdx.x * MT;
  for (int t = tid; t < MT * 64; t += 256) {
    int p = t >> 6, c = t & 63;
    int row = base + p; if (row >= NN) row = NN - 1;
    float4 v = *reinterpret_cast<const float4*>(&x[(size_t)row * HDIM + c * 4]);
    unsigned short tmp[4] = {f2bs(v.x), f2bs(v.y), f2bs(v.z), f2bs(v.w)};
    *reinterpret_cast<uint2*>(&A[p][c * 4]) = *reinterpret_cast<const uint2*>(tmp);
  }
  __syncthreads();
  int j0 = w * 64;
#pragma unroll
  for (int mtx = 0; mtx < 3; ++mtx) {
    const unsigned short* Ws = (mtx == 0) ? Wqs : (mtx == 1) ? Wks : Wvs;
    bf16* outp = (mtx == 0) ? qs : (mtx == 1) ? ks : vv;
    f32x4 acc[4][4];
#pragma unroll
    for (int m = 0; m < 4; ++m)
#pragma unroll
      for (int n = 0; n < 4; ++n)
#pragma unroll
        for (int r = 0; r < 4; ++r) acc[m][n][r] = 0.f;
    for (int k0 = 0; k0 < 8; ++k0) {
      bf16x8 a[4], b[4];
#pragma unroll
      for (int m = 0; m < 4; ++m)
        a[m] = *reinterpret_cast<const bf16x8*>(&A[m * 16 + lr][k0 * 32 + lk * 8]);
#pragma unroll
      for (int n = 0; n < 4; ++n) {
        int nt = (j0 >> 4) + n;
        b[n] = *reinterpret_cast<const bf16x8*>(Ws + ((size_t)(nt * 8 + k0) * 64 + l) * 8);
      }
#pragma unroll
      for (int m = 0; m < 4; ++m)
#pragma unroll
        for (int n = 0; n < 4; ++n)
          acc[m][n] = __builtin_amdgcn_mfma_f32_16x16x32_bf16(a[m], b[n], acc[m][n], 0, 0, 0);
    }
    if (mtx < 2) {
      float pa[4][4], pb[4][4];
#pragma unroll
      for (int m = 0; m < 4; ++m)
#pragma unroll
        for (int r = 0; r < 4; ++r) {
          pa[m][r] = acc[m][0][r] * acc[m][0][r] + acc[m][1][r] * acc[m][1][r];
          pb[m][r] = acc[m][2][r] * acc[m][2][r] + acc[m][3][r] * acc[m][3][r];
        }
#pragma unroll
      for (int off = 1; off < 16; off <<= 1) {
#pragma unroll
        for (int m = 0; m < 4; ++m)
#pragma unroll
          for (int r = 0; r < 4; ++r) {
            pa[m][r] += __shfl_xor(pa[m][r], off);
            pb[m][r] += __shfl_xor(pb[m][r], off);
          }
      }
#pragma unroll
      for (int m = 0; m < 4; ++m)
#pragma unroll
        for (int r = 0; r < 4; ++r) {
          float ra = 1.f / (sqrtf(pa[m][r]) + 1e-6f);
          float rb = 1.f / (sqrtf(pb[m][r]) + 1e-6f);
          acc[m][0][r] *= ra; acc[m][1][r] *= ra;
          acc[m][2][r] *= rb; acc[m][3][r] *= rb;
        }
    }
#pragma unroll
    for (int n = 0; n < 4; ++n)
#pragma unroll
      for (int m = 0; m < 4; ++m)
#pragma unroll
        for (int r = 0; r < 4; ++r)
          O[m * 16 + lk * 4 + r][j0 + n * 16 + lr] = f2bs(acc[m][n][r]);
    __syncthreads();
    for (int t = tid; t < MT * 32; t += 256) {
      int p = t >> 5, c = t & 31;
      if (base + p < NN)
        *reinterpret_cast<uint4*>(&outp[(size_t)(base + p) * HDIM + c * 8]) =
            *reinterpret_cast<const uint4*>(&O[p][c * 8]);
    }
    __syncthreads();
  }
}

// ---- sg_kv stage 1: per-block partials (NO atomics) ---------------------------------
__global__ void k_sg_kv1(const bf16* __restrict__ ks, const bf16* __restrict__ vv,
                         float* __restrict__ part) {
  int t = threadIdx.x;
  int h = t >> 5;
  float kvloc[CH];
  float ksl = 0.f;
#pragma unroll
  for (int d = 0; d < CH; ++d) kvloc[d] = 0.f;
  __shared__ float krow[HDIM], vrow[HDIM];
  for (int n = blockIdx.x; n < NN; n += KVB) {
    krow[t] = b2f(ks[(size_t)n * HDIM + t]);
    vrow[t] = b2f(vv[(size_t)n * HDIM + t]);
    __syncthreads();
    float kc = krow[t];
    ksl += kc;
#pragma unroll
    for (int d = 0; d < CH; ++d) kvloc[d] += kc * vrow[h * CH + d];
    __syncthreads();
  }
  float* dstp = part + (size_t)blockIdx.x * 8448;
#pragma unroll
  for (int d = 0; d < CH; d += 4)
    *reinterpret_cast<float4*>(&dstp[t * CH + d]) =
        *reinterpret_cast<const float4*>(&kvloc[d]);
  dstp[8192 + t] = ksl;
}

// ---- sg_kv stage 2: deterministic reduce over KVB partials --------------------------
__global__ void k_sg_kv2(const float* __restrict__ part, float* __restrict__ kv,
                         float* __restrict__ ksum) {
  int idx = blockIdx.x * 256 + threadIdx.x;
  if (idx >= 8448) return;
  float s = 0.f;
  for (int b = 0; b < KVB; ++b) s += part[(size_t)b * 8448 + idx];
  if (idx < 8192) kv[idx] = s;
  else ksum[idx - 8192] = s;
}

// ---- trans + combine + LN -> f32 out ------------------------------------------------
__global__ void k_sg_final(const bf16* __restrict__ qs, const bf16* __restrict__ vv,
                           const float* __restrict__ kv, const float* __restrict__ ksum,
                           const float* __restrict__ xg, const float* __restrict__ alphap,
                           const float* __restrict__ cng, const float* __restrict__ cnb,
                           float* __restrict__ out) {
  int t = threadIdx.x;
  int d = t & 31, sub = t >> 5;
  __shared__ float qrow[8][HDIM];
  __shared__ float crow[8][CH];
  int n = blockIdx.x * 8 + sub;
  for (int tt = t; tt < 8 * HDIM; tt += 256) {
    int p = tt >> 8, k = tt & 255;
    int n2 = blockIdx.x * 8 + p;
    if (n2 < NN) qrow[p][k] = b2f(qs[(size_t)n2 * HDIM + k]);
  }
  __syncthreads();
  float alpha = 1.f / (1.f + expf(-alphap[0]));
  const float Nf = (float)NN;
  float comb = 0.f;
  if (n < NN) {
    float acc = 0.f;
#pragma unroll
    for (int h = 0; h < NH; ++h) {
      float nm = 0.f, dp = 0.f;
#pragma unroll 8
      for (int c = 0; c < CH; ++c) {
        float qv = qrow[sub][h * CH + c];
        nm += qv * kv[(h * CH + c) * CH + d];
        dp += qv * ksum[h * CH + c];
      }
      nm += Nf * b2f(vv[(size_t)n * HDIM + h * CH + d]);
      acc += nm / (dp + Nf);
    }
    float trans = acc * (1.f / NH);
    comb = alpha * xg[(size_t)n * CH + d] + (1.f - alpha) * trans;
    crow[sub][d] = comb;
  }
  __syncthreads();
  if (n < NN) {
    float mu = 0.f;
#pragma unroll
    for (int k = 0; k < CH; ++k) mu += crow[sub][k];
    mu *= (1.f / CH);
    float var = 0.f;
#pragma unroll
    for (int k = 0; k < CH; ++k) { float dv = crow[sub][k] - mu; var += dv * dv; }
    var *= (1.f / CH);
    float o = (comb - mu) * rsqrtf(var + 1e-5f) * cng[d] + cnb[d];
    out[(size_t)n * CH + d] = o;
  }
}

extern "C" void kernel_launch(void* const* d_in, const int* in_sizes, int n_in,
                              void* d_out, int out_size, void* d_ws, size_t ws_size,
                              hipStream_t stream) {
  const float* mesh  = (const float*)d_in[0];
  const int*   eidx  = (const int*)d_in[1];
  const float* eattr = (const float*)d_in[2];
  const float* epW   = (const float*)d_in[3];
  const float* epb   = (const float*)d_in[4];
  const float* Wl0   = (const float*)d_in[5];
  const float* Wr0   = (const float*)d_in[6];
  const float* WlL   = (const float*)d_in[7];
  const float* WrL   = (const float*)d_in[8];
  const float* We0   = (const float*)d_in[9];
  const float* WeL   = (const float*)d_in[10];
  const float* att0  = (const float*)d_in[11];
  const float* attL  = (const float*)d_in[12];
  const float* Wres0 = (const float*)d_in[13];
  const float* WresL = (const float*)d_in[14];
  const float* bn0   = (const float*)d_in[15];
  const float* bnL   = (const float*)d_in[16];
  const float* Wu1_0 = (const float*)d_in[17];
  const float* Wu1L  = (const float*)d_in[18];
  const float* bu1_0 = (const float*)d_in[19];
  const float* bu1L  = (const float*)d_in[20];
  const float* Wu2_0 = (const float*)d_in[21];
  const float* Wu2L  = (const float*)d_in[22];
  const float* bu2_0 = (const float*)d_in[23];
  const float* bu2L  = (const float*)d_in[24];
  const float* lng   = (const float*)d_in[25];
  const float* lnb   = (const float*)d_in[26];
  const float* Wq    = (const float*)d_in[27];
  const float* Wk    = (const float*)d_in[28];
  const float* Wv    = (const float*)d_in[29];
  const float* alphap= (const float*)d_in[30];
  const float* cng   = (const float*)d_in[31];
  const float* cnb   = (const float*)d_in[32];

  const int* src = eidx;
  const int* dst = eidx + NE;

  char* base = (char*)d_ws;
  size_t o = 0;
  auto alloc = [&](size_t bytes) -> char* {
    o = (o + 255) & ~(size_t)255;
    char* p = base + o;
    o += bytes;
    return p;
  };
  bf16* e    = (bf16*)alloc((size_t)NE * HDIM * 2);
  bf16* xl   = (bf16*)alloc((size_t)NN * HDIM * 2);
  bf16* xr   = (bf16*)alloc((size_t)NN * HDIM * 2);
  bf16* vvb  = (bf16*)alloc((size_t)NN * HDIM * 2);
  float* sxc = (float*)alloc((size_t)NE * NH * 4);    // exp(scores), CSR-ordered
  float* xa  = (float*)alloc((size_t)NN * CH * 4);
  float* xb  = (float*)alloc((size_t)NN * CH * 4);
  float* xc  = (float*)alloc((size_t)NN * CH * 4);
  float* kv  = (float*)alloc(NH * CH * CH * 4);
  float* ksum= (float*)alloc(NH * CH * 4);
  float* kvpart = (float*)alloc((size_t)KVB * 8448 * 4);   // 17.3 MB
  unsigned short* w1s = (unsigned short*)alloc((size_t)3 * 320 * 256 * 2);
  unsigned short* w2s = (unsigned short*)alloc((size_t)3 * 256 * 256 * 2);
  unsigned short* wall= (unsigned short*)alloc((size_t)9 * 65536 * 2);
  unsigned short* w32s= (unsigned short*)alloc((size_t)6 * 32 * 256 * 2);
  unsigned short* wep = (unsigned short*)alloc((size_t)SWZ_N4 * 2);
  int* cnt    = (int*)alloc((size_t)NN * 4);
  int* rowptr = (int*)alloc((size_t)(NN + 1) * 4);
  int* cursor = (int*)alloc((size_t)NN * 4);
  int* csrsrc = (int*)alloc((size_t)NE * 4);
  int* pos    = (int*)alloc((size_t)NE * 4);
  if (ws_size < o) return;   // fail cleanly if ws too small

  // fused pre-pass: all weight swizzles (incl. epW) + cnt zeroing in ONE launch
  SwzP P;
  P.We0 = We0; P.WeL = WeL; P.Wl0 = Wl0; P.Wr0 = Wr0; P.Wq = Wq; P.Wk = Wk; P.Wv = Wv;
  P.Wu1_0 = Wu1_0; P.Wu1L = Wu1L; P.Wu2_0 = Wu2_0; P.Wu2L = Wu2L;
  P.WlL = WlL; P.WrL = WrL; P.epW = epW;
  P.wall = wall; P.w1s = w1s; P.w2s = w2s; P.w32s = w32s; P.wep = wep; P.cnt = cnt;
  int swz_total = SWZ_NW + SWZ_N1 + SWZ_N2 + SWZ_N3 + SWZ_N4 + NN;
  k_swz_fused<<<(swz_total + 255) / 256, 256, 0, stream>>>(P);

  // CSR build (graph constant across layers); pos[e] = CSR slot of edge e
  k_csr_count<<<(NE + 255) / 256, 256, 0, stream>>>(dst, cnt);
  k_csr_scan<<<1, 256, 0, stream>>>(cnt, rowptr, cursor);
  k_csr_fill<<<(NE + 255) / 256, 256, 0, stream>>>(src, dst, cursor, csrsrc, pos);

  k_edge_proj_mfma<<<NE / MT, 512, 0, stream>>>(eattr, wep, epb, e);

  const float* xin = mesh;
  float* post = xb;
  for (int l = 0; l < 4; ++l) {
    const float *att_p, *Wres_p, *bn_p, *bu1_p, *bu2_p;
    if (l == 0) {
      att_p = att0; Wres_p = Wres0; bn_p = bn0; bu1_p = bu1_0; bu2_p = bu2_0;
    } else {
      int i = l - 1;
      att_p = attL + (size_t)i * HDIM;
      Wres_p = WresL + (size_t)i * CH * CH;
      bn_p = bnL + (size_t)i * CH;
      bu1_p = bu1L + (size_t)i * HDIM;
      bu2_p = bu2L + (size_t)i * HDIM;
    }

    if (l == 0)
      k_node_proj0_mfma<<<(NN + MT - 1) / MT, 256, 0, stream>>>(
          mesh, wall + (size_t)4 * 65536, wall + (size_t)5 * 65536, xl, xr);
    else
      k_node_projS_mfma<<<(NN + MT - 1) / MT, 256, 0, stream>>>(
          xin, w32s + (size_t)((l - 1) * 2 + 0) * 8192,
          w32s + (size_t)((l - 1) * 2 + 1) * 8192, xl, xr);

    k_edge_score_mfma<<<NE / MT, 512, 0, stream>>>(e, wall + (size_t)l * 65536,
                                                   xl, xr, att_p, src, dst, pos, sxc);

    if (l == 0)
      k_gat_out<HDIM, true><<<NN, 256, 0, stream>>>(rowptr, csrsrc, sxc, xl, xin, Wres_p,
                                                    bn_p, lng, lnb, xa, post);
    else if (l < 3)
      k_gat_out<CH, true><<<NN, 256, 0, stream>>>(rowptr, csrsrc, sxc, xl, xin, Wres_p,
                                                  bn_p, lng + (size_t)l * CH,
                                                  lnb + (size_t)l * CH, xa, post);
    else
      k_gat_out<CH, false><<<NN, 256, 0, stream>>>(rowptr, csrsrc, sxc, xl, xin, Wres_p,
                                                   bn_p, nullptr, nullptr, xa, nullptr);

    if (l < 3)
      k_edge_mlp_mfma<<<NE / MT, 512, 0, stream>>>(e, xa, src, dst,
                                                   w1s + (size_t)l * 320 * 256, bu1_p,
                                                   w2s + (size_t)l * 256 * 256, bu2_p);

    xin = post;
    post = (post == xb) ? xc : xb;
  }
  // final GAT output (no LN) is in xa

  k_sg_qkv_mfma<<<(NN + MT - 1) / MT, 256, 0, stream>>>(
      mesh, wall + (size_t)6 * 65536, wall + (size_t)7 * 65536,
      wall + (size_t)8 * 65536, xl, xr, vvb);
  k_sg_kv1<<<KVB, 256, 0, stream>>>(xr, vvb, kvpart);
  k_sg_kv2<<<33, 256, 0, stream>>>(kvpart, kv, ksum);
  k_sg_final<<<(NN + 7) / 8, 256, 0, stream>>>(xl, vvb, kv, ksum, xa, alphap, cng, cnb,
                                               (float*)d_out);
}